// Round 4
// baseline (2126.876 us; speedup 1.0000x reference)
//
#include <hip/hip_runtime.h>
#include <hip/hip_bf16.h>
#include <hip/hip_cooperative_groups.h>

namespace cg = cooperative_groups;

#define B_DIM 1024
#define H_DIM 2048
#define V_DIM 8192
#define L_DIM 8

typedef __attribute__((ext_vector_type(8))) __bf16 bf16x8;
typedef __attribute__((ext_vector_type(4))) __bf16 bf16x4;
typedef __attribute__((ext_vector_type(4))) float f32x4;
typedef unsigned short u16;

#define ASM_BARRIER() asm volatile("s_barrier" ::: "memory")
#define WAIT_VM12() asm volatile("s_waitcnt vmcnt(12)" ::: "memory")
#define WAIT_VM8() asm volatile("s_waitcnt vmcnt(8)" ::: "memory")
#define WAIT_VM4() asm volatile("s_waitcnt vmcnt(4)" ::: "memory")
#define WAIT_VM0() asm volatile("s_waitcnt vmcnt(0)" ::: "memory")

// async 16B/lane global->LDS. LDS dest = wave-uniform base + lane*16.
__device__ __forceinline__ void async_copy16(const void* g, void* l) {
  __builtin_amdgcn_global_load_lds(
      (const unsigned int __attribute__((address_space(1)))*)g,
      (unsigned int __attribute__((address_space(3)))*)l,
      16, 0, 0);
}

// ============================================================================
// FUSED persistent kernel: hh transpose (all layers) + state convert + 8
// fused GEMM+gather+tanh layers, grid.sync() between layers.
// 512 blocks x 256 threads, 64 KiB LDS -> exactly 2 blocks/CU co-resident.
// Cross-XCD visibility at layer boundaries: __threadfence() (agent-scope
// fence = buffer_wbl2/buffer_inv sc1) both sides of each grid.sync(),
// replacing the implicit cache ops kernel boundaries used to provide.
// ============================================================================
__global__ __launch_bounds__(256, 2) void rnn_fused(
    const float* __restrict__ state, const int* __restrict__ token,
    const float* __restrict__ ih, const float* __restrict__ hh,
    __bf16* __restrict__ hhT, float* __restrict__ F0, float* __restrict__ F1,
    __bf16* __restrict__ Sb0, __bf16* __restrict__ Sb1,
    float* __restrict__ dout) {
  __shared__ __align__(16) __bf16 As[4][4096];
  __shared__ __align__(16) __bf16 Bs[4][4096];
  cg::grid_group grid = cg::this_grid();
  int bid = blockIdx.x;
  int tid = threadIdx.x;

  // ---------------- phase A: hh fp32 [L][K][N] -> hhT bf16 [L][N][K] -------
  // 8192 64x64 tiles total, 16 per block, staged through (aliased) LDS.
  {
    __bf16(*tile)[67] = (__bf16(*)[67])(&As[0][0]);  // 64*67*2 B < 32 KiB
    for (int i = 0; i < 16; ++i) {
      int g = bid * 16 + i;
      int l = g >> 10;
      int t = g & 1023;
      int k0 = (t >> 5) << 6;
      int n0 = (t & 31) << 6;
      const float* hh_l = hh + ((size_t)l << 22);
      __bf16* hhT_l = hhT + ((size_t)l << 22);
      if (i) __syncthreads();  // previous tile's readers done
      {
        int r = tid >> 2;              // 0..63
        int c = (tid & 3) << 4;        // 0,16,32,48
        const float4* src =
            (const float4*)(hh_l + (size_t)(k0 + r) * H_DIM + n0 + c);
#pragma unroll
        for (int q = 0; q < 4; q++) {
          float4 v = src[q];
          tile[r][c + q * 4 + 0] = (__bf16)v.x;
          tile[r][c + q * 4 + 1] = (__bf16)v.y;
          tile[r][c + q * 4 + 2] = (__bf16)v.z;
          tile[r][c + q * 4 + 3] = (__bf16)v.w;
        }
      }
      __syncthreads();
      {
        int n = tid >> 2;              // 0..63
        int kq = (tid & 3) << 4;       // 0,16,32,48
        alignas(16) u16 tmp[16];
#pragma unroll
        for (int j = 0; j < 16; j++) {
          __bf16 b = tile[kq + j][n];
          tmp[j] = *(const u16*)&b;
        }
        uint4* dst = (uint4*)(hhT_l + (size_t)(n0 + n) * H_DIM + k0 + kq);
        dst[0] = *(uint4*)(tmp);
        dst[1] = *(uint4*)(tmp + 8);
      }
    }
  }
  // ---------------- phase B: state fp32 -> bf16 (layer-0 A operand) --------
  {
    const float4* in = (const float4*)state;
    bf16x4* out = (bf16x4*)Sb0;
    int base = bid * 256 + tid;        // 131072 threads, 524288 float4s
#pragma unroll
    for (int it = 0; it < 4; ++it) {
      int i = base + it * 131072;
      float4 v = in[i];
      bf16x4 o;
      o.x = (__bf16)v.x; o.y = (__bf16)v.y; o.z = (__bf16)v.z; o.w = (__bf16)v.w;
      out[i] = o;
    }
  }
  __threadfence();   // release: hhT/Sb0 visible device-wide
  grid.sync();
  __threadfence();   // acquire: invalidate stale L1/L2 copies

  // ---------------- layer-invariant geometry -------------------------------
  // XCD swizzle: 8 mi x 8 ni tiles per XCD (bid&7 round-robins XCDs)
  int x = bid & 7;
  int rest = bid >> 3;
  int mi = (x & 1) * 8 + (rest & 7);       // 0..15
  int ni = (x >> 1) * 8 + (rest >> 3);     // 0..31
  int bm0 = mi * 64;
  int bn0 = ni * 64;

  int w = tid >> 6;
  int lane = tid & 63;
  int rsub = lane >> 3;            // row within 8-row slot
  int csw = (lane & 7) ^ rsub;     // XOR-swizzled source chunk (16B units)
  int slot0 = (w * 2 + 0) * 512;
  int slot1 = (w * 2 + 1) * 512;
  int wm = (w >> 1) * 32;
  int wn = (w & 1) * 32;
  int col = lane & 15;
  int quad = lane >> 4;
  int c7 = lane & 7;

  size_t offA0 = (size_t)(bm0 + (w * 2 + 0) * 8 + rsub) * H_DIM + csw * 8;
  size_t offA1 = (size_t)(bm0 + (w * 2 + 1) * 8 + rsub) * H_DIM + csw * 8;
  size_t offB0 = (size_t)(bn0 + (w * 2 + 0) * 8 + rsub) * H_DIM + csw * 8;
  size_t offB1 = (size_t)(bn0 + (w * 2 + 1) * 8 + rsub) * H_DIM + csw * 8;

  // ---------------- 8 layers, grid-synced ----------------------------------
#pragma unroll 1
  for (int l = 0; l < L_DIM; ++l) {
    const __bf16* Acur = (l & 1) ? Sb1 : Sb0;
    const __bf16* Bt = hhT + ((size_t)l << 22);
    const float* S = (l == 0) ? state : ((l & 1) ? F0 : F1);
    const float* ih_l = ih + ((size_t)l << 24);
    float* OutF = (l == L_DIM - 1) ? dout : ((l & 1) ? F1 : F0);
    __bf16* OutB = (l & 1) ? Sb0 : Sb1;
    const bool lastL = (l == L_DIM - 1);

    const __bf16* pA0 = Acur + offA0;
    const __bf16* pA1 = Acur + offA1;
    const __bf16* pB0 = Bt + offB0;
    const __bf16* pB1 = Bt + offB1;

    constexpr int NT = H_DIM / 64;   // 32 K-tiles
    f32x4 acc[2][2] = {};

    auto issue = [&](int buf, int kt) {
      int ko = kt * 64;
      async_copy16(pA0 + ko, &As[buf][slot0]);
      async_copy16(pA1 + ko, &As[buf][slot1]);
      async_copy16(pB0 + ko, &Bs[buf][slot0]);
      async_copy16(pB1 + ko, &Bs[buf][slot1]);
    };
    auto compute = [&](int buf) {
#pragma unroll
      for (int ks = 0; ks < 2; ks++) {
        int cc = ks * 4 + quad;
        bf16x8 a0 = *(const bf16x8*)(&As[buf][(wm + 0 + col) * 64 + ((cc ^ c7) * 8)]);
        bf16x8 a1 = *(const bf16x8*)(&As[buf][(wm + 16 + col) * 64 + ((cc ^ c7) * 8)]);
        bf16x8 b0 = *(const bf16x8*)(&Bs[buf][(wn + 0 + col) * 64 + ((cc ^ c7) * 8)]);
        bf16x8 b1 = *(const bf16x8*)(&Bs[buf][(wn + 16 + col) * 64 + ((cc ^ c7) * 8)]);
        acc[0][0] = __builtin_amdgcn_mfma_f32_16x16x32_bf16(a0, b0, acc[0][0], 0, 0, 0);
        acc[0][1] = __builtin_amdgcn_mfma_f32_16x16x32_bf16(a0, b1, acc[0][1], 0, 0, 0);
        acc[1][0] = __builtin_amdgcn_mfma_f32_16x16x32_bf16(a1, b0, acc[1][0], 0, 0, 0);
        acc[1][1] = __builtin_amdgcn_mfma_f32_16x16x32_bf16(a1, b1, acc[1][1], 0, 0, 0);
      }
    };

    // 3 tiles in flight; counted vmcnt(12) in steady state, never drained.
    issue(0, 0);
    issue(1, 1);
    issue(2, 2);
    for (int t = 0; t < NT - 3; ++t) {
      issue((t + 3) & 3, t + 3);
      WAIT_VM12();       // retire tile t only; t+1..t+3 stay in flight
      ASM_BARRIER();
      compute(t & 3);
      ASM_BARRIER();     // all waves done reading buf t&3
    }
    WAIT_VM8();
    ASM_BARRIER();
    compute((NT - 3) & 3);
    ASM_BARRIER();
    WAIT_VM4();
    ASM_BARRIER();
    compute((NT - 2) & 3);
    ASM_BARRIER();
    WAIT_VM0();
    ASM_BARRIER();
    compute((NT - 1) & 3);

    // epilogue: C/D layout col=lane&15, row=quad*4+reg
#pragma unroll
    for (int mt = 0; mt < 2; mt++) {
#pragma unroll
      for (int reg = 0; reg < 4; reg++) {
        int b = bm0 + wm + mt * 16 + quad * 4 + reg;
        int tok = token[b];
        const float* ihrow = ih_l + (size_t)tok * H_DIM;
        size_t rowoff = (size_t)b * H_DIM;
#pragma unroll
        for (int nt = 0; nt < 2; nt++) {
          int h = bn0 + wn + nt * 16 + col;
          float g = ihrow[h];
          float sv = S[rowoff + h];
          float v = tanhf(fmaf(acc[mt][nt][reg], g, sv));
          OutF[rowoff + h] = v;
          if (!lastL) OutB[rowoff + h] = (__bf16)v;
        }
      }
    }

    if (!lastL) {
      __threadfence();   // release OutF/OutB (drains vmcnt -> counts stay valid)
      grid.sync();
      __threadfence();   // acquire: invalidate stale lines on reader XCDs
    }
  }
}

// ============================================================================
// Fallback path (old 10-dispatch chain) in case cooperative launch is
// rejected under graph capture.
// ============================================================================
__global__ __launch_bounds__(256) void rnn_conv_state(
    const float4* __restrict__ in, bf16x4* __restrict__ out) {
  int i = blockIdx.x * 256 + threadIdx.x;
  float4 v = in[i];
  bf16x4 o;
  o.x = (__bf16)v.x; o.y = (__bf16)v.y; o.z = (__bf16)v.z; o.w = (__bf16)v.w;
  out[i] = o;
}

__global__ __launch_bounds__(256) void rnn_hh_transpose_all(
    const float* __restrict__ hh, __bf16* __restrict__ hhT) {
  int bid = blockIdx.x;
  int l = bid >> 10;
  int t = bid & 1023;
  int k0 = (t >> 5) << 6;
  int n0 = (t & 31) << 6;
  __shared__ __bf16 tile[64][67];
  int tid = threadIdx.x;
  const float* hh_l = hh + ((size_t)l << 22);
  __bf16* hhT_l = hhT + ((size_t)l << 22);
  {
    int r = tid >> 2;
    int c = (tid & 3) << 4;
    const float4* src = (const float4*)(hh_l + (size_t)(k0 + r) * H_DIM + n0 + c);
#pragma unroll
    for (int q = 0; q < 4; q++) {
      float4 v = src[q];
      tile[r][c + q * 4 + 0] = (__bf16)v.x;
      tile[r][c + q * 4 + 1] = (__bf16)v.y;
      tile[r][c + q * 4 + 2] = (__bf16)v.z;
      tile[r][c + q * 4 + 3] = (__bf16)v.w;
    }
  }
  __syncthreads();
  {
    int n = tid >> 2;
    int kq = (tid & 3) << 4;
    alignas(16) u16 tmp[16];
#pragma unroll
    for (int j = 0; j < 16; j++) {
      __bf16 b = tile[kq + j][n];
      tmp[j] = *(const u16*)&b;
    }
    uint4* dst = (uint4*)(hhT_l + (size_t)(n0 + n) * H_DIM + k0 + kq);
    dst[0] = *(uint4*)(tmp);
    dst[1] = *(uint4*)(tmp + 8);
  }
}

__global__ __launch_bounds__(256) void rnn_layer_pipe(
    const __bf16* __restrict__ A, const __bf16* __restrict__ Bt,
    const float* __restrict__ S, const float* __restrict__ ih_l,
    const int* __restrict__ token,
    float* __restrict__ OutF, __bf16* __restrict__ OutB) {
  constexpr int K = H_DIM;
  constexpr int NT = K / 64;
  __shared__ __align__(16) __bf16 As[4][64 * 64];
  __shared__ __align__(16) __bf16 Bs[4][64 * 64];

  int bid = blockIdx.x;
  int x = bid & 7;
  int rest = bid >> 3;
  int mi = (x & 1) * 8 + (rest & 7);
  int ni = (x >> 1) * 8 + (rest >> 3);
  int bm0 = mi * 64;
  int bn0 = ni * 64;

  int tid = threadIdx.x;
  int w = tid >> 6;
  int lane = tid & 63;
  int rsub = lane >> 3;
  int csw = (lane & 7) ^ rsub;

  const __bf16* pA0 = A + (size_t)(bm0 + (w * 2 + 0) * 8 + rsub) * K + csw * 8;
  const __bf16* pA1 = A + (size_t)(bm0 + (w * 2 + 1) * 8 + rsub) * K + csw * 8;
  const __bf16* pB0 = Bt + (size_t)(bn0 + (w * 2 + 0) * 8 + rsub) * K + csw * 8;
  const __bf16* pB1 = Bt + (size_t)(bn0 + (w * 2 + 1) * 8 + rsub) * K + csw * 8;
  int slot0 = (w * 2 + 0) * 512;
  int slot1 = (w * 2 + 1) * 512;

  int wm = (w >> 1) * 32;
  int wn = (w & 1) * 32;
  int col = lane & 15;
  int quad = lane >> 4;
  int c7 = lane & 7;

  f32x4 acc[2][2] = {};

  auto issue = [&](int buf, int kt) {
    int ko = kt * 64;
    async_copy16(pA0 + ko, &As[buf][slot0]);
    async_copy16(pA1 + ko, &As[buf][slot1]);
    async_copy16(pB0 + ko, &Bs[buf][slot0]);
    async_copy16(pB1 + ko, &Bs[buf][slot1]);
  };
  auto compute = [&](int buf) {
#pragma unroll
    for (int ks = 0; ks < 2; ks++) {
      int cc = ks * 4 + quad;
      bf16x8 a0 = *(const bf16x8*)(&As[buf][(wm + 0 + col) * 64 + ((cc ^ c7) * 8)]);
      bf16x8 a1 = *(const bf16x8*)(&As[buf][(wm + 16 + col) * 64 + ((cc ^ c7) * 8)]);
      bf16x8 b0 = *(const bf16x8*)(&Bs[buf][(wn + 0 + col) * 64 + ((cc ^ c7) * 8)]);
      bf16x8 b1 = *(const bf16x8*)(&Bs[buf][(wn + 16 + col) * 64 + ((cc ^ c7) * 8)]);
      acc[0][0] = __builtin_amdgcn_mfma_f32_16x16x32_bf16(a0, b0, acc[0][0], 0, 0, 0);
      acc[0][1] = __builtin_amdgcn_mfma_f32_16x16x32_bf16(a0, b1, acc[0][1], 0, 0, 0);
      acc[1][0] = __builtin_amdgcn_mfma_f32_16x16x32_bf16(a1, b0, acc[1][0], 0, 0, 0);
      acc[1][1] = __builtin_amdgcn_mfma_f32_16x16x32_bf16(a1, b1, acc[1][1], 0, 0, 0);
    }
  };

  issue(0, 0);
  issue(1, 1);
  issue(2, 2);
  for (int t = 0; t < NT - 3; ++t) {
    issue((t + 3) & 3, t + 3);
    WAIT_VM12();
    ASM_BARRIER();
    compute(t & 3);
    ASM_BARRIER();
  }
  WAIT_VM8();
  ASM_BARRIER();
  compute((NT - 3) & 3);
  ASM_BARRIER();
  WAIT_VM4();
  ASM_BARRIER();
  compute((NT - 2) & 3);
  ASM_BARRIER();
  WAIT_VM0();
  ASM_BARRIER();
  compute((NT - 1) & 3);

#pragma unroll
  for (int mt = 0; mt < 2; mt++) {
#pragma unroll
    for (int reg = 0; reg < 4; reg++) {
      int b = bm0 + wm + mt * 16 + quad * 4 + reg;
      int tok = token[b];
      const float* ihrow = ih_l + (size_t)tok * H_DIM;
      size_t rowoff = (size_t)b * H_DIM;
#pragma unroll
      for (int nt = 0; nt < 2; nt++) {
        int h = bn0 + wn + nt * 16 + col;
        float g = ihrow[h];
        float sv = S[rowoff + h];
        float v = tanhf(fmaf(acc[mt][nt][reg], g, sv));
        OutF[rowoff + h] = v;
        OutB[rowoff + h] = (__bf16)v;
      }
    }
  }
}

extern "C" void kernel_launch(void* const* d_in, const int* in_sizes, int n_in,
                              void* d_out, int out_size, void* d_ws, size_t ws_size,
                              hipStream_t stream) {
  const float* state = (const float*)d_in[0];
  const int* token = (const int*)d_in[1];
  const float* ih = (const float*)d_in[2];
  const float* hh = (const float*)d_in[3];

  // ws layout (88 MiB used):
  char* ws = (char*)d_ws;
  __bf16* hhT = (__bf16*)ws;                    // 8*2048*2048*2 = 67108864 B
  float* F0 = (float*)(ws + 67108864);          // 8388608 B
  float* F1 = (float*)(ws + 75497472);          // 8388608 B
  __bf16* Sb0 = (__bf16*)(ws + 83886080);       // 4194304 B
  __bf16* Sb1 = (__bf16*)(ws + 88080384);       // 4194304 B
  float* dout = (float*)d_out;

  void* args[] = {(void*)&state, (void*)&token, (void*)&ih, (void*)&hh,
                  (void*)&hhT,   (void*)&F0,    (void*)&F1, (void*)&Sb0,
                  (void*)&Sb1,   (void*)&dout};
  hipError_t err = hipLaunchCooperativeKernel(
      (const void*)rnn_fused, dim3(512), dim3(256), args, 0, stream);

  if (err != hipSuccess) {
    // Fallback: old 10-dispatch chain.
    rnn_hh_transpose_all<<<8192, 256, 0, stream>>>(hh, hhT);
    rnn_conv_state<<<2048, 256, 0, stream>>>((const float4*)state, (bf16x4*)Sb0);
    const float* Sprev = state;
    for (int l = 0; l < L_DIM; l++) {
      const __bf16* hhT_l = hhT + ((size_t)l << 22);
      const float* ih_l = ih + ((size_t)l << 24);
      const __bf16* Acur = (l & 1) ? Sb1 : Sb0;
      __bf16* outB = (l & 1) ? Sb0 : Sb1;
      float* outF = (l == L_DIM - 1) ? (float*)d_out : ((l & 1) ? F1 : F0);
      rnn_layer_pipe<<<512, 256, 0, stream>>>(Acur, hhT_l, Sprev, ih_l, token,
                                              outF, (__bf16*)outB);
      Sprev = outF;
    }
  }
}

// Round 6
// 850.886 us; speedup vs baseline: 2.4996x; 2.4996x over previous
//
#include <hip/hip_runtime.h>
#include <hip/hip_bf16.h>

#define B_DIM 1024
#define H_DIM 2048
#define V_DIM 8192
#define L_DIM 8

typedef __attribute__((ext_vector_type(8))) __bf16 bf16x8;
typedef __attribute__((ext_vector_type(4))) __bf16 bf16x4;
typedef __attribute__((ext_vector_type(4))) float f32x4;
typedef unsigned short u16;

#define ASM_BARRIER() asm volatile("s_barrier" ::: "memory")
#define WAIT_VM12() asm volatile("s_waitcnt vmcnt(12)" ::: "memory")
#define WAIT_VM8() asm volatile("s_waitcnt vmcnt(8)" ::: "memory")
#define WAIT_VM4() asm volatile("s_waitcnt vmcnt(4)" ::: "memory")
#define WAIT_VM0() asm volatile("s_waitcnt vmcnt(0)" ::: "memory")

// async 16B/lane global->LDS. LDS dest = wave-uniform base + lane*16.
__device__ __forceinline__ void async_copy16(const void* g, void* l) {
  __builtin_amdgcn_global_load_lds(
      (const unsigned int __attribute__((address_space(1)))*)g,
      (unsigned int __attribute__((address_space(3)))*)l,
      16, 0, 0);
}

// ---------- prep: hh transpose (blocks 0..8191) + state convert (8192..10239)
// hh fp32 [L][K][N] -> hhT bf16 [L][N][K]; 64x64 tiles through LDS.
__global__ __launch_bounds__(256) void rnn_prep(
    const float* __restrict__ hh, __bf16* __restrict__ hhT,
    const float4* __restrict__ state, bf16x4* __restrict__ Sb0) {
  int bid = blockIdx.x;
  int tid = threadIdx.x;
  if (bid >= 8192) {
    // state fp32 -> bf16 (layer-0 A operand): 2048 blocks x 256 thr x 16B
    int i = (bid - 8192) * 256 + tid;
    float4 v = state[i];
    bf16x4 o;
    o.x = (__bf16)v.x; o.y = (__bf16)v.y; o.z = (__bf16)v.z; o.w = (__bf16)v.w;
    Sb0[i] = o;
    return;
  }
  int l = bid >> 10;
  int t = bid & 1023;
  int k0 = (t >> 5) << 6;
  int n0 = (t & 31) << 6;
  __shared__ __bf16 tile[64][67];
  const float* hh_l = hh + ((size_t)l << 22);
  __bf16* hhT_l = hhT + ((size_t)l << 22);
  {
    int r = tid >> 2;               // 0..63
    int c = (tid & 3) << 4;         // 0,16,32,48
    const float4* src = (const float4*)(hh_l + (size_t)(k0 + r) * H_DIM + n0 + c);
#pragma unroll
    for (int q = 0; q < 4; q++) {
      float4 v = src[q];
      tile[r][c + q * 4 + 0] = (__bf16)v.x;
      tile[r][c + q * 4 + 1] = (__bf16)v.y;
      tile[r][c + q * 4 + 2] = (__bf16)v.z;
      tile[r][c + q * 4 + 3] = (__bf16)v.w;
    }
  }
  __syncthreads();
  {
    int n = tid >> 2;               // 0..63
    int kq = (tid & 3) << 4;        // 0,16,32,48
    alignas(16) u16 tmp[16];
#pragma unroll
    for (int j = 0; j < 16; j++) {
      __bf16 b = tile[kq + j][n];
      tmp[j] = *(const u16*)&b;
    }
    uint4* dst = (uint4*)(hhT_l + (size_t)(n0 + n) * H_DIM + k0 + kq);
    dst[0] = *(uint4*)(tmp);
    dst[1] = *(uint4*)(tmp + 8);
  }
}

// ---------- per-layer fused GEMM + gather + tanh, software-pipelined --------
// C[b][h] = tanh(S[b][h] + (A @ hh_l)[b][h] * ih_l[token[b]][h])
// 4-buffer LDS, 3 k-tiles in flight (counted vmcnt(12), never drained in the
// main loop). Token/S/ih epilogue operands are prefetched in the prologue,
// BEFORE the tile pipeline starts -- their loads are the OLDEST vmcnt
// entries, so the first WAIT_VM12 retires them together with tile 0 and
// every later counted wait is unchanged. Their HBM latency hides under the
// 32-phase K-loop instead of serializing after it.
__global__ __launch_bounds__(256) void rnn_layer_pipe(
    const __bf16* __restrict__ A, const __bf16* __restrict__ Bt,
    const float* __restrict__ S, const float* __restrict__ ih_l,
    const int* __restrict__ token,
    float* __restrict__ OutF, __bf16* __restrict__ OutB) {
  constexpr int K = H_DIM;
  constexpr int NT = K / 64;       // 32 K-tiles
  __shared__ __align__(16) __bf16 As[4][64 * 64];
  __shared__ __align__(16) __bf16 Bs[4][64 * 64];

  // XCD swizzle: 8 mi x 8 ni tiles per XCD (bid&7 round-robins XCDs)
  int bid = blockIdx.x;
  int x = bid & 7;
  int rest = bid >> 3;
  int mi = (x & 1) * 8 + (rest & 7);       // 0..15
  int ni = (x >> 1) * 8 + (rest >> 3);     // 0..31
  int bm0 = mi * 64;
  int bn0 = ni * 64;

  int tid = threadIdx.x;
  int w = tid >> 6;
  int lane = tid & 63;
  int rsub = lane >> 3;            // row within 8-row slot
  int csw = (lane & 7) ^ rsub;     // XOR-swizzled source chunk (16B units)

  // LDS phys chunk p at within-slot row r holds logical chunk p ^ r
  const __bf16* pA0 = A + (size_t)(bm0 + (w * 2 + 0) * 8 + rsub) * K + csw * 8;
  const __bf16* pA1 = A + (size_t)(bm0 + (w * 2 + 1) * 8 + rsub) * K + csw * 8;
  const __bf16* pB0 = Bt + (size_t)(bn0 + (w * 2 + 0) * 8 + rsub) * K + csw * 8;
  const __bf16* pB1 = Bt + (size_t)(bn0 + (w * 2 + 1) * 8 + rsub) * K + csw * 8;
  int slot0 = (w * 2 + 0) * 512;
  int slot1 = (w * 2 + 1) * 512;

  int wm = (w >> 1) * 32;
  int wn = (w & 1) * 32;
  int col = lane & 15;
  int quad = lane >> 4;
  int c7 = lane & 7;

  // ---- epilogue-operand prefetch (issued before any tile load) ----
  // 8 token + 16 S + 16 ih loads; all fully unrolled constant-index arrays
  // -> registers (no scratch). token->ih dependency forces one
  // compiler-inserted vmcnt wait here (the 16 younger S loads may retire
  // with it); values are consumed only in the epilogue, after WAIT_VM0 has
  // already retired everything (zero-cost waits).
  int tokv[2][4];
#pragma unroll
  for (int mt = 0; mt < 2; mt++)
#pragma unroll
    for (int reg = 0; reg < 4; reg++)
      tokv[mt][reg] = token[bm0 + wm + mt * 16 + quad * 4 + reg];
  float sv[2][4][2];
#pragma unroll
  for (int mt = 0; mt < 2; mt++)
#pragma unroll
    for (int reg = 0; reg < 4; reg++) {
      size_t rowoff = (size_t)(bm0 + wm + mt * 16 + quad * 4 + reg) * H_DIM;
#pragma unroll
      for (int nt = 0; nt < 2; nt++)
        sv[mt][reg][nt] = S[rowoff + bn0 + wn + nt * 16 + col];
    }
  float gv[2][4][2];
#pragma unroll
  for (int mt = 0; mt < 2; mt++)
#pragma unroll
    for (int reg = 0; reg < 4; reg++) {
      const float* ihrow = ih_l + (size_t)tokv[mt][reg] * H_DIM;
#pragma unroll
      for (int nt = 0; nt < 2; nt++)
        gv[mt][reg][nt] = ihrow[bn0 + wn + nt * 16 + col];
    }

  f32x4 acc[2][2] = {};

  auto issue = [&](int buf, int kt) {
    int ko = kt * 64;
    async_copy16(pA0 + ko, &As[buf][slot0]);
    async_copy16(pA1 + ko, &As[buf][slot1]);
    async_copy16(pB0 + ko, &Bs[buf][slot0]);
    async_copy16(pB1 + ko, &Bs[buf][slot1]);
  };
  auto compute = [&](int buf) {
#pragma unroll
    for (int ks = 0; ks < 2; ks++) {
      int cc = ks * 4 + quad;       // logical 16B chunk (k = cc*8 .. +7)
      bf16x8 a0 = *(const bf16x8*)(&As[buf][(wm + 0 + col) * 64 + ((cc ^ c7) * 8)]);
      bf16x8 a1 = *(const bf16x8*)(&As[buf][(wm + 16 + col) * 64 + ((cc ^ c7) * 8)]);
      bf16x8 b0 = *(const bf16x8*)(&Bs[buf][(wn + 0 + col) * 64 + ((cc ^ c7) * 8)]);
      bf16x8 b1 = *(const bf16x8*)(&Bs[buf][(wn + 16 + col) * 64 + ((cc ^ c7) * 8)]);
      acc[0][0] = __builtin_amdgcn_mfma_f32_16x16x32_bf16(a0, b0, acc[0][0], 0, 0, 0);
      acc[0][1] = __builtin_amdgcn_mfma_f32_16x16x32_bf16(a0, b1, acc[0][1], 0, 0, 0);
      acc[1][0] = __builtin_amdgcn_mfma_f32_16x16x32_bf16(a1, b0, acc[1][0], 0, 0, 0);
      acc[1][1] = __builtin_amdgcn_mfma_f32_16x16x32_bf16(a1, b1, acc[1][1], 0, 0, 0);
    }
  };

  // Prologue: 3 tiles in flight (prefetch loads are older in the vm queue).
  issue(0, 0);
  issue(1, 1);
  issue(2, 2);
  // Main loop. First WAIT_VM12: outstanding = epilogue prefetch + 16 tile
  // loads; waiting to 12 retires all prefetch + tile-0's 4. Steady state
  // after that is the usual counted-vmcnt schedule (retire exactly one tile).
  for (int t = 0; t < NT - 3; ++t) {
    issue((t + 3) & 3, t + 3);
    WAIT_VM12();       // retire tile t; t+1..t+3 stay in flight
    ASM_BARRIER();     // all waves' tile-t data now in LDS
    compute(t & 3);
    ASM_BARRIER();     // all waves done reading buf t&3
  }
  // Tail: drain 3 remaining tiles (29,30,31 -> bufs 1,2,3).
  WAIT_VM8();
  ASM_BARRIER();
  compute((NT - 3) & 3);
  ASM_BARRIER();
  WAIT_VM4();
  ASM_BARRIER();
  compute((NT - 2) & 3);
  ASM_BARRIER();
  WAIT_VM0();
  ASM_BARRIER();
  compute((NT - 1) & 3);

  // epilogue: C/D layout col=lane&15, row=quad*4+reg; all operands in regs
#pragma unroll
  for (int mt = 0; mt < 2; mt++) {
#pragma unroll
    for (int reg = 0; reg < 4; reg++) {
      size_t rowoff = (size_t)(bm0 + wm + mt * 16 + quad * 4 + reg) * H_DIM;
#pragma unroll
      for (int nt = 0; nt < 2; nt++) {
        int h = bn0 + wn + nt * 16 + col;
        float v = tanhf(fmaf(acc[mt][nt][reg], gv[mt][reg][nt], sv[mt][reg][nt]));
        OutF[rowoff + h] = v;
        OutB[rowoff + h] = (__bf16)v;
      }
    }
  }
}

extern "C" void kernel_launch(void* const* d_in, const int* in_sizes, int n_in,
                              void* d_out, int out_size, void* d_ws, size_t ws_size,
                              hipStream_t stream) {
  const float* state = (const float*)d_in[0];
  const int* token = (const int*)d_in[1];
  const float* ih = (const float*)d_in[2];
  const float* hh = (const float*)d_in[3];

  // ws layout (88 MiB used):
  char* ws = (char*)d_ws;
  __bf16* hhT = (__bf16*)ws;                    // 8*2048*2048*2 = 67108864 B
  float* F0 = (float*)(ws + 67108864);          // 8388608 B
  float* F1 = (float*)(ws + 75497472);          // 8388608 B
  __bf16* Sb0 = (__bf16*)(ws + 83886080);       // 4194304 B
  __bf16* Sb1 = (__bf16*)(ws + 88080384);       // 4194304 B

  // weight transpose (all layers) + state convert, one dispatch
  rnn_prep<<<10240, 256, 0, stream>>>(hh, hhT, (const float4*)state,
                                      (bf16x4*)Sb0);

  const float* Sprev = state;                   // fp32 residual
  for (int l = 0; l < L_DIM; l++) {
    const __bf16* hhT_l = hhT + ((size_t)l << 22);
    const float* ih_l = ih + ((size_t)l << 24);
    const __bf16* Acur = (l & 1) ? Sb1 : Sb0;
    __bf16* outB = (l & 1) ? Sb0 : Sb1;
    float* outF = (l == L_DIM - 1) ? (float*)d_out : ((l & 1) ? F1 : F0);
    rnn_layer_pipe<<<512, 256, 0, stream>>>(Acur, hhT_l, Sprev, ih_l, token,
                                            outF, outB);
    Sprev = outF;
  }
}